// Round 1
// baseline (555.185 us; speedup 1.0000x reference)
//
#include <hip/hip_runtime.h>
#include <cstdint>
#include <cstddef>

static constexpr int DIN  = 64;
static constexpr int DHID = 128;
static constexpr int DOUT = 64;

// ====================== edge dtype detect + extract ======================
// Reference uses int64 edge_index; harness doc suggests int32. Detect on-device:
// interpret first 256 slots as int64 — if all in [0,N) it's int64 (prob of
// misdetection with int32 data ~ (1e-5)^256 = 0).
__global__ __launch_bounds__(64) void detect_kernel(const void* edges, int E, long long nmax, int* mode) {
  const long long* e64 = (const long long*)edges;
  int lane = threadIdx.x;
  int nchk = E < 256 ? E : 256;
  bool ok = true;
  for (int i = lane; i < nchk; i += 64) {
    long long v = e64[i];
    if (v < 0 || v >= nmax) ok = false;
  }
  unsigned long long b = __ballot(ok);
  if (lane == 0) *mode = (b == ~0ull) ? 1 : 0;
}

__global__ __launch_bounds__(256) void extract_kernel(const void* edges, const int* __restrict__ mode,
                                                      int* __restrict__ src, int* __restrict__ dst, int E) {
  int i = blockIdx.x * 256 + threadIdx.x;
  if (i >= E) return;
  if (*mode) {
    const long long* e = (const long long*)edges;
    src[i] = (int)e[i];
    dst[i] = (int)e[(size_t)E + i];
  } else {
    const int* e = (const int*)edges;
    src[i] = e[i];
    dst[i] = e[(size_t)E + i];
  }
}

// ====================== CSR build (sort edges by dst) ======================
__global__ __launch_bounds__(256) void hist_kernel(const int* __restrict__ dst, int* __restrict__ deg, int E) {
  int i = blockIdx.x * 256 + threadIdx.x;
  if (i < E) atomicAdd(&deg[dst[i]], 1);
}

// block = 256 threads, 4 elems/thread -> 1024 elems/block. Exclusive scan local
// to block written to excl[], block total to blockSums[].
__global__ __launch_bounds__(256) void scan1_kernel(const int* __restrict__ deg, int* __restrict__ excl,
                                                    int* __restrict__ blockSums, int N) {
  int t = threadIdx.x;
  int i0 = blockIdx.x * 1024 + t * 4;
  int v[4]; int s = 0;
  #pragma unroll
  for (int c = 0; c < 4; ++c) { int idx = i0 + c; v[c] = (idx < N) ? deg[idx] : 0; s += v[c]; }
  int lane = t & 63, w = t >> 6;
  int val = s;
  #pragma unroll
  for (int off = 1; off < 64; off <<= 1) {
    int u = __shfl_up(val, off, 64);
    if (lane >= off) val += u;
  }
  __shared__ int wsum[4];
  if (lane == 63) wsum[w] = val;
  __syncthreads();
  int wpre = 0;
  for (int ww = 0; ww < w; ++ww) wpre += wsum[ww];
  int run = wpre + val - s;  // exclusive prefix of this thread's 4-chunk
  #pragma unroll
  for (int c = 0; c < 4; ++c) { int idx = i0 + c; if (idx < N) excl[idx] = run; run += v[c]; }
  if (t == 255) blockSums[blockIdx.x] = wpre + val;
}

__global__ __launch_bounds__(64) void scan2_kernel(int* blockSums, int nb) {
  if (threadIdx.x == 0) {
    int run = 0;
    for (int b = 0; b < nb; ++b) { int t = blockSums[b]; blockSums[b] = run; run += t; }
  }
}

__global__ __launch_bounds__(256) void scan3_kernel(int* __restrict__ row_ptr, int* __restrict__ cursor,
                                                    const int* __restrict__ blockOffs, int N, int E) {
  int i = blockIdx.x * 256 + threadIdx.x;
  if (i < N) {
    int r = row_ptr[i] + blockOffs[i >> 10];
    row_ptr[i] = r;
    cursor[i] = r;
  }
  if (i == 0) row_ptr[N] = E;
}

__global__ __launch_bounds__(256) void fill_kernel(const int* __restrict__ src, const int* __restrict__ dst,
                                                   int* __restrict__ cursor, int* __restrict__ sorted_src, int E) {
  int i = blockIdx.x * 256 + threadIdx.x;
  if (i >= E) return;
  int pos = atomicAdd(&cursor[dst[i]], 1);
  sorted_src[pos] = src[i];
}

// ====================== mean aggregation over in-neighbors ======================
// One wave per node; lane holds D/64 consecutive feature floats.
template <int D>
__global__ __launch_bounds__(256) void agg_mean_kernel(const float* __restrict__ feat,
                                                       const int* __restrict__ row_ptr,
                                                       const int* __restrict__ srcs,
                                                       float* __restrict__ out, int N) {
  constexpr int V = D / 64;
  int wid = (int)(((size_t)blockIdx.x * 256 + threadIdx.x) >> 6);
  int lane = threadIdx.x & 63;
  if (wid >= N) return;
  int beg = row_ptr[wid], end = row_ptr[wid + 1];
  float acc[V];
  #pragma unroll
  for (int c = 0; c < V; ++c) acc[c] = 0.f;
  int e = beg;
  for (; e + 4 <= end; e += 4) {  // unroll 4: overlap gather latency
    int s0 = srcs[e], s1 = srcs[e + 1], s2 = srcs[e + 2], s3 = srcs[e + 3];
    const float* p0 = feat + (size_t)s0 * D + lane * V;
    const float* p1 = feat + (size_t)s1 * D + lane * V;
    const float* p2 = feat + (size_t)s2 * D + lane * V;
    const float* p3 = feat + (size_t)s3 * D + lane * V;
    #pragma unroll
    for (int c = 0; c < V; ++c) acc[c] += (p0[c] + p1[c]) + (p2[c] + p3[c]);
  }
  for (; e < end; ++e) {
    const float* p = feat + (size_t)srcs[e] * D + lane * V;
    #pragma unroll
    for (int c = 0; c < V; ++c) acc[c] += p[c];
  }
  float inv = 1.f / fmaxf((float)(end - beg), 1.f);
  #pragma unroll
  for (int c = 0; c < V; ++c) out[(size_t)wid * D + lane * V + c] = acc[c] * inv;
}

// ====================== 2-source GEMM: C = [Aa‖Ab] @ [Wa‖Wb].T + bias ======================
// BM=BN=BK=64, 256 threads, 4x4 register tile per thread. A stored transposed
// in LDS (k-major) so both a- and b-fragments are contiguous float4 reads.
__global__ __launch_bounds__(256) void gemm2src_kernel(
    const float* __restrict__ Aa, const float* __restrict__ Ab,
    const float* __restrict__ Wa, const float* __restrict__ Wb,
    const float* __restrict__ bias, float* __restrict__ C,
    int M, int NOUT, int K1, int K2, int do_relu)
{
  constexpr int BM = 64, BN = 64, BK = 64;
  __shared__ __align__(16) float As[BK][BM + 4];
  __shared__ __align__(16) float Bs[BK][BN + 4];
  int m0 = blockIdx.x * BM;
  int j0 = blockIdx.y * BN;
  int t = threadIdx.x;
  int tx = t & 15, ty = t >> 4;
  float acc[4][4];
  #pragma unroll
  for (int i = 0; i < 4; ++i)
    #pragma unroll
    for (int j = 0; j < 4; ++j) acc[i][j] = 0.f;
  int KTOT = K1 + K2;
  for (int kc = 0; kc < KTOT; kc += BK) {
    const float* Asrc; const float* Wsrc; int ld, kb;
    if (kc < K1) { Asrc = Aa; Wsrc = Wa; ld = K1; kb = kc; }
    else         { Asrc = Ab; Wsrc = Wb; ld = K2; kb = kc - K1; }
    #pragma unroll
    for (int i = 0; i < 16; ++i) {
      int idx = i * 256 + t;
      int r = idx >> 6, kk = idx & 63;
      int row = m0 + r;
      As[kk][r] = (row < M) ? Asrc[(size_t)row * ld + kb + kk] : 0.f;
      Bs[kk][r] = Wsrc[(size_t)(j0 + r) * ld + kb + kk];  // j0+r < NOUT always
    }
    __syncthreads();
    #pragma unroll 8
    for (int kk = 0; kk < BK; ++kk) {
      float4 a4 = *(const float4*)&As[kk][ty * 4];
      float4 b4 = *(const float4*)&Bs[kk][tx * 4];
      float av[4] = {a4.x, a4.y, a4.z, a4.w};
      float bv[4] = {b4.x, b4.y, b4.z, b4.w};
      #pragma unroll
      for (int i = 0; i < 4; ++i)
        #pragma unroll
        for (int j = 0; j < 4; ++j) acc[i][j] += av[i] * bv[j];
    }
    __syncthreads();
  }
  #pragma unroll
  for (int i = 0; i < 4; ++i) {
    int row = m0 + ty * 4 + i;
    if (row >= M) continue;
    float4 o;
    float* po = (float*)&o;
    #pragma unroll
    for (int j = 0; j < 4; ++j) {
      float v = acc[i][j] + bias[j0 + tx * 4 + j];
      if (do_relu) v = fmaxf(v, 0.f);
      po[j] = v;
    }
    *(float4*)&C[(size_t)row * NOUT + j0 + tx * 4] = o;
  }
}

// ====================== launch ======================
extern "C" void kernel_launch(void* const* d_in, const int* in_sizes, int n_in,
                              void* d_out, int out_size, void* d_ws, size_t ws_size,
                              hipStream_t stream) {
  const float* x   = (const float*)d_in[0];
  const void*  ei  = d_in[1];
  const float* Wl1 = (const float*)d_in[2];
  const float* bl1 = (const float*)d_in[3];
  const float* Wr1 = (const float*)d_in[4];
  const float* Wl2 = (const float*)d_in[5];
  const float* bl2 = (const float*)d_in[6];
  const float* Wr2 = (const float*)d_in[7];
  int N = in_sizes[0] / DIN;
  int E = in_sizes[1] / 2;

  char* w = (char*)d_ws;
  size_t off = 0;
  auto alloc = [&](size_t bytes) -> void* {
    void* p = w + off;
    off += (bytes + 255) & ~(size_t)255;
    return p;
  };
  int*   mode       = (int*)alloc(16);
  int*   src        = (int*)alloc((size_t)E * 4);
  int*   dstA       = (int*)alloc((size_t)E * 4);
  int*   deg        = (int*)alloc((size_t)N * 4);
  int*   row_ptr    = (int*)alloc(((size_t)N + 1) * 4);
  int*   cursor     = (int*)alloc((size_t)N * 4);
  int*   blockSums  = (int*)alloc(4096);
  int*   sorted_src = (int*)alloc((size_t)E * 4);
  float* meanbuf    = (float*)alloc((size_t)N * DHID * 4);  // mean1 (N*64) then mean2 (N*128); lifetimes disjoint
  float* h          = (float*)alloc((size_t)N * DHID * 4);
  (void)ws_size; (void)n_in; (void)out_size;

  hipMemsetAsync(deg, 0, (size_t)N * 4, stream);

  detect_kernel<<<1, 64, 0, stream>>>(ei, E, (long long)N, mode);
  int gE = (E + 255) / 256;
  extract_kernel<<<gE, 256, 0, stream>>>(ei, mode, src, dstA, E);
  hist_kernel<<<gE, 256, 0, stream>>>(dstA, deg, E);
  int nb = (N + 1023) / 1024;
  scan1_kernel<<<nb, 256, 0, stream>>>(deg, row_ptr, blockSums, N);
  scan2_kernel<<<1, 64, 0, stream>>>(blockSums, nb);
  scan3_kernel<<<(N + 255) / 256, 256, 0, stream>>>(row_ptr, cursor, blockSums, N, E);
  fill_kernel<<<gE, 256, 0, stream>>>(src, dstA, cursor, sorted_src, E);

  int gN4 = (N + 3) / 4;  // 4 waves/block, wave per node
  agg_mean_kernel<DIN><<<gN4, 256, 0, stream>>>(x, row_ptr, sorted_src, meanbuf, N);

  dim3 g1((N + 63) / 64, DHID / 64);
  gemm2src_kernel<<<g1, 256, 0, stream>>>(meanbuf, x, Wl1, Wr1, bl1, h, N, DHID, DIN, DIN, 1);

  agg_mean_kernel<DHID><<<gN4, 256, 0, stream>>>(h, row_ptr, sorted_src, meanbuf, N);

  dim3 g2((N + 63) / 64, DOUT / 64);
  gemm2src_kernel<<<g2, 256, 0, stream>>>(meanbuf, h, Wl2, Wr2, bl2, (float*)d_out, N, DOUT, DHID, DHID, 0);
}